// Round 7
// baseline (113.292 us; speedup 1.0000x reference)
//
#include <hip/hip_runtime.h>
#include <hip/hip_bf16.h>

#define NBATCH 4
#define NN 4096
#define NF 128
#define NU 64
#define CH 16              // correction chunk length
#define NCH (NN / CH)      // 256 chunks per batch
#define LEAKY 0.2f

// ---------------------------------------------------------------------------
// k1: h[b,n,u] = sum_f x[b,n,f]*W[f,u]; f1 = h.a1, f2 = h.a2.
// NEW MAPPING: 256 blocks x 256 thr; lane owns one row (64 rows/block);
// wave wv owns u-tile [16*wv, 16*wv+16). x per-lane float4 (L1-resident:
// 64 rows x 512B = 32KB); W/a via uniform s_load (SGPR operand in v_fma).
// No DS in main loop. (LDS-broadcast version cost ~10us, DS-pipe bound;
// R5's all-scalar-x version regressed — x must stay on the vector path.)
// ---------------------------------------------------------------------------
__global__ __launch_bounds__(256) void k1_h(
    const float* __restrict__ x, const float* __restrict__ W,
    const float* __restrict__ a,
    float* __restrict__ h, float* __restrict__ f1, float* __restrict__ f2) {
  __shared__ float p1s[4][64], p2s[4][64];
  int tid = threadIdx.x;
  int lane = tid & 63;
  int wv = __builtin_amdgcn_readfirstlane(tid >> 6);   // provably uniform
  int u0 = wv * 16;
  int row = blockIdx.x * 64 + lane;
  const float* xr = x + (size_t)row * NF;
  float acc[16];
#pragma unroll
  for (int i = 0; i < 16; ++i) acc[i] = 0.f;
#pragma unroll 8
  for (int f = 0; f < NF; f += 4) {
    float4 xv = *(const float4*)(xr + f);              // per-lane vmem
#pragma unroll
    for (int i = 0; i < 4; ++i) {
      const float* wr = W + (size_t)(f + i) * NU + u0; // uniform -> s_load
      float xf = (i == 0) ? xv.x : (i == 1) ? xv.y : (i == 2) ? xv.z : xv.w;
#pragma unroll
      for (int uu = 0; uu < 16; ++uu)
        acc[uu] += xf * wr[uu];                        // SGPR operand fma
    }
  }
  // write h row-slice: 16 contiguous u's = 4 float4 stores
  float* hr = h + (size_t)row * NU + u0;
#pragma unroll
  for (int q = 0; q < 4; ++q) {
    float4 v;
    v.x = acc[4*q+0]; v.y = acc[4*q+1]; v.z = acc[4*q+2]; v.w = acc[4*q+3];
    *(float4*)(hr + 4*q) = v;
  }
  // partial f1/f2 over this wave's u-tile (a loads uniform -> s_load)
  float p1 = 0.f, p2 = 0.f;
#pragma unroll
  for (int uu = 0; uu < 16; ++uu) {
    p1 += acc[uu] * a[u0 + uu];
    p2 += acc[uu] * a[NU + u0 + uu];
  }
  p1s[wv][lane] = p1;
  p2s[wv][lane] = p2;
  __syncthreads();
  if (tid < 64) {
    int grow = blockIdx.x * 64 + tid;
    f1[grow] = p1s[0][tid] + p1s[1][tid] + p1s[2][tid] + p1s[3][tid];
    f2[grow] = p2s[0][tid] + p2s[1][tid] + p2s[2][tid] + p2s[3][tid];
  }
}

// ---------------------------------------------------------------------------
// k2a: partial rank counts. grid = b(4) x jc(8: 512 j) x kc(16: 256 k) = 512.
// Thread owns 2 j's; float4 LDS reads (8 compares per DS instr).
// ---------------------------------------------------------------------------
__global__ __launch_bounds__(256) void k2a_count(
    const float* __restrict__ f2, unsigned short* __restrict__ pc) {
  __shared__ float fsk[256];
  int b = blockIdx.x >> 7;          // 128 blocks per batch
  int jc = (blockIdx.x >> 4) & 7;
  int kc = blockIdx.x & 15;
  int tid = threadIdx.x;
  const float* f2b = f2 + b * NN;
  fsk[tid] = f2b[kc * 256 + tid];
  __syncthreads();
  int j0 = jc * 512 + tid;
  int j1 = j0 + 256;
  float my0 = f2b[j0], my1 = f2b[j1];
  int k0g = kc * 256;
  int cnt0 = 0, cnt1 = 0;
#pragma unroll 8
  for (int k = 0; k < 256; k += 4) {
    float4 v = *(const float4*)&fsk[k];
    int kg = k0g + k;
    cnt0 += (v.x < my0) || (v.x == my0 && kg + 0 < j0);
    cnt0 += (v.y < my0) || (v.y == my0 && kg + 1 < j0);
    cnt0 += (v.z < my0) || (v.z == my0 && kg + 2 < j0);
    cnt0 += (v.w < my0) || (v.w == my0 && kg + 3 < j0);
    cnt1 += (v.x < my1) || (v.x == my1 && kg + 0 < j1);
    cnt1 += (v.y < my1) || (v.y == my1 && kg + 1 < j1);
    cnt1 += (v.z < my1) || (v.z == my1 && kg + 2 < j1);
    cnt1 += (v.w < my1) || (v.w == my1 && kg + 3 < j1);
  }
  size_t base = ((size_t)(b * 16 + kc)) * NN;
  pc[base + j0] = (unsigned short)cnt0;
  pc[base + j1] = (unsigned short)cnt1;
}

// ---------------------------------------------------------------------------
// k2b: rank = sum of 16 partials; scatter packed {f2, e^f2, e^.2f2, perm}
// plus a plain sorted-f2 array. 256 blocks x 64 thr (1 wave per CU spread).
// ---------------------------------------------------------------------------
__global__ __launch_bounds__(64) void k2b_scatter(
    const float* __restrict__ f2, const unsigned short* __restrict__ pc,
    float4* __restrict__ sdat, float* __restrict__ f2s) {
  int g = blockIdx.x * 64 + threadIdx.x;   // [0, B*N)
  int b = g >> 12;
  int j = g & (NN - 1);
  float my = f2[b * NN + j];
  int rank = 0;
#pragma unroll
  for (int kc = 0; kc < 16; ++kc)
    rank += pc[((size_t)(b * 16 + kc)) * NN + j];
  int o = b * NN + rank;
  float4 v;
  v.x = my; v.y = expf(my); v.z = expf(LEAKY * my); v.w = __int_as_float(j);
  sdat[o] = v;
  f2s[o] = my;
}

// ---------------------------------------------------------------------------
// k3: chunk sums. One wave per chunk of CH=16 sorted els; lane = u.
// 256 blocks x 4 waves.
// ---------------------------------------------------------------------------
__global__ __launch_bounds__(256) void k3_csum(
    const float* __restrict__ h, const float4* __restrict__ sdat,
    float* __restrict__ Pvhi, float* __restrict__ Pvlo,
    float* __restrict__ Pshi, float* __restrict__ Pslo) {
  int u = threadIdx.x & 63;
  int wv = threadIdx.x >> 6;
  int cg = blockIdx.x * 4 + wv;     // global chunk 0..1023
  int b = cg >> 8;                  // 256 chunks per batch
  int c = cg & (NCH - 1);
  int k0 = b * NN + c * CH;
  const float* hb = h + (size_t)b * NN * NU;
  float ah = 0.f, al = 0.f, sh = 0.f, sl = 0.f;
#pragma unroll
  for (int k = 0; k < CH; ++k) {
    float4 e = sdat[k0 + k];
    int j = __float_as_int(e.w);
    float hv = hb[(size_t)j * NU + u];
    ah += e.y * hv; al += e.z * hv; sh += e.y; sl += e.z;
  }
  size_t o = (size_t)(b * (NCH + 1) + c) * NU + u;
  Pvhi[o] = ah; Pvlo[o] = al;
  if (u == 0) { Pshi[b * (NCH + 1) + c] = sh; Pslo[b * (NCH + 1) + c] = sl; }
}

// ---------------------------------------------------------------------------
// k3b: in-place exclusive shuffle-scan of NCH=256 chunk sums (4 per lane);
// slot [NCH] = total. wid<512: vector tables; wid in [512,520): scalars.
// ---------------------------------------------------------------------------
__global__ __launch_bounds__(256) void k3b_scan(
    float* __restrict__ Pvhi, float* __restrict__ Pvlo,
    float* __restrict__ Pshi, float* __restrict__ Pslo) {
  int wid = blockIdx.x * 4 + (threadIdx.x >> 6);
  int l = threadIdx.x & 63;
  if (wid < 512) {
    int b = wid >> 7;
    int half = (wid >> 6) & 1;
    int u = wid & 63;
    float* T = half ? Pvlo : Pvhi;
    size_t i0 = (size_t)(b * (NCH + 1) + 4 * l) * NU + u;
    float v0 = T[i0], v1 = T[i0 + NU], v2 = T[i0 + 2*NU], v3 = T[i0 + 3*NU];
    float lsum = v0 + v1 + v2 + v3, s = lsum;
#pragma unroll
    for (int off = 1; off < 64; off <<= 1) {
      float t = __shfl_up(s, off, 64);
      if (l >= off) s += t;
    }
    float e = s - lsum;            // exclusive prefix of this lane's chunks
    T[i0] = e;
    T[i0 + NU] = e + v0;
    T[i0 + 2*NU] = e + v0 + v1;
    T[i0 + 3*NU] = e + v0 + v1 + v2;
    if (l == 63) T[(size_t)(b * (NCH + 1) + NCH) * NU + u] = s;
  } else if (wid < 520) {
    int s2 = wid - 512;
    int b = s2 >> 1;
    float* T = (s2 & 1) ? Pslo : Pshi;
    int i0 = b * (NCH + 1) + 4 * l;
    float v0 = T[i0], v1 = T[i0 + 1], v2 = T[i0 + 2], v3 = T[i0 + 3];
    float lsum = v0 + v1 + v2 + v3, s = lsum;
#pragma unroll
    for (int off = 1; off < 64; off <<= 1) {
      float t = __shfl_up(s, off, 64);
      if (l >= off) s += t;
    }
    float e = s - lsum;
    T[i0] = e; T[i0 + 1] = e + v0; T[i0 + 2] = e + v0 + v1;
    T[i0 + 3] = e + v0 + v1 + v2;
    if (l == 63) T[b * (NCH + 1) + NCH] = s;
  }
}

// ---------------------------------------------------------------------------
// k4: per row: 2-round ballot lower_bound, chunk-table lookup, CH=16 exact
// correction over the straddling chunk, combine, write. wave = row; lane = u.
// ---------------------------------------------------------------------------
__global__ __launch_bounds__(256) void k4_out(
    const float* __restrict__ f1, const float* __restrict__ f2s,
    const float* __restrict__ h, const float4* __restrict__ sdat,
    const float* __restrict__ Pvhi, const float* __restrict__ Pvlo,
    const float* __restrict__ Pshi, const float* __restrict__ Pslo,
    float* __restrict__ out) {
  int u = threadIdx.x & 63;
  int wv = threadIdx.x >> 6;
  int row = blockIdx.x * 4 + wv;    // [0, B*N)
  int b = row >> 12;
  const float* fs = f2s + b * NN;
  float fv = f1[row];
  float theta = -fv;
  // fan-out lower_bound: first t with fs[t] >= theta
  float q1 = fs[u * 64 + 63];
  int n1 = __popcll(__ballot(q1 < theta));   // # 64-blocks entirely < theta
  int t;
  if (n1 == 64) {
    t = NN;
  } else {
    float q2 = fs[n1 * 64 + u];
    t = n1 * 64 + __popcll(__ballot(q2 < theta));
  }
  int c = t >> 4; if (c > NCH - 1) c = NCH - 1;
  int k0 = b * NN + c * CH;
  const float* hb = h + (size_t)b * NN * NU;
  float ch = 0.f, cl = 0.f, csh = 0.f, csl = 0.f;
#pragma unroll
  for (int k = 0; k < CH; ++k) {
    int kg = c * CH + k;
    float4 e = sdat[k0 + k];
    int j = __float_as_int(e.w);
    float hv = hb[(size_t)j * NU + u];
    bool hi = (kg >= t);
    float wH = hi ? e.y : 0.f;
    float wL = hi ? 0.f : e.z;
    ch += wH * hv; cl += wL * hv; csh += wH; csl += wL;
  }
  size_t base = (size_t)b * (NCH + 1);
  size_t oc0 = (base + c) * NU + u;
  size_t oc1 = (base + c + 1) * NU + u;
  size_t oT  = (base + NCH) * NU + u;
  float Ahi = (Pvhi[oT] - Pvhi[oc1]) + ch;
  float Alo = Pvlo[oc0] + cl;
  float Shi = (Pshi[base + NCH] - Pshi[base + c + 1]) + csh;
  float Slo = Pslo[base + c] + csl;
  float e1 = expf(fv), e1l = expf(LEAKY * fv);
  float den = e1 * Shi + e1l * Slo;
  out[(size_t)row * NU + u] = (e1 * Ahi + e1l * Alo) / den;
}

// ---------------------------------------------------------------------------
extern "C" void kernel_launch(void* const* d_in, const int* in_sizes, int n_in,
                              void* d_out, int out_size, void* d_ws, size_t ws_size,
                              hipStream_t stream) {
  const float* x = (const float*)d_in[0];   // (4,4096,128) f32
  const float* W = (const float*)d_in[1];   // (128,64) f32
  const float* a = (const float*)d_in[2];   // (128,1) f32
  float* out = (float*)d_out;               // (4,4096,64) f32
  float* ws = (float*)d_ws;

  size_t o = 0;
  float* h    = ws + o; o += (size_t)NBATCH * NN * NU;        // 4 MB
  float* f1   = ws + o; o += (size_t)NBATCH * NN;
  float* f2   = ws + o; o += (size_t)NBATCH * NN;
  float* f2s  = ws + o; o += (size_t)NBATCH * NN;
  float4* sdat = (float4*)(ws + o); o += (size_t)NBATCH * NN * 4;  // 16B aligned
  float* Pvhi = ws + o; o += (size_t)NBATCH * (NCH + 1) * NU;
  float* Pvlo = ws + o; o += (size_t)NBATCH * (NCH + 1) * NU;
  float* Pshi = ws + o; o += (size_t)NBATCH * (NCH + 1);
  float* Pslo = ws + o; o += (size_t)NBATCH * (NCH + 1);
  unsigned short* pc = (unsigned short*)(ws + o); o += (size_t)NBATCH * 16 * NN / 2;
  // ~6 MB of ws

  k1_h<<<(NBATCH * NN) / 64, 256, 0, stream>>>(x, W, a, h, f1, f2);
  k2a_count<<<512, 256, 0, stream>>>(f2, pc);
  k2b_scatter<<<(NBATCH * NN) / 64, 64, 0, stream>>>(f2, pc, sdat, f2s);
  k3_csum<<<(NBATCH * NCH) / 4, 256, 0, stream>>>(h, sdat, Pvhi, Pvlo, Pshi, Pslo);
  k3b_scan<<<130, 256, 0, stream>>>(Pvhi, Pvlo, Pshi, Pslo);
  k4_out<<<(NBATCH * NN) / 4, 256, 0, stream>>>(f1, f2s, h, sdat,
      Pvhi, Pvlo, Pshi, Pslo, out);
}